// Round 14
// baseline (97.885 us; speedup 1.0000x reference)
//
#include <hip/hip_runtime.h>
#include <stdint.h>
#include <math.h>

#define B_N 512
#define M_N 65536
#define D_N 256
#define C_N 10
#define TEMP_INV 14.285714285714286f   // 1/0.07
#define LOG2E_F 1.4426950408889634f
#define K2C (LOG2E_F * TEMP_INV)       // exp(x/T) = exp2(x*K2C)

typedef __attribute__((ext_vector_type(8))) __bf16 bf16x8;
typedef __attribute__((ext_vector_type(4))) float f32x4;

__device__ __forceinline__ unsigned short f2bf(float f) {
  unsigned int u = __float_as_uint(f);
  return (unsigned short)((u + 0x7FFFu + ((u >> 16) & 1u)) >> 16);  // RNE
}
__device__ __forceinline__ float bf2f(unsigned short s) {
  return __uint_as_float(((unsigned int)s) << 16);
}

// K1: q normalize (32 blocks x 256 thr): q -> f32 qn + bf16 qnb (row-major)
// + qnbF (k-chunk-major [kc][r][8] for GEMM A-fragments). Block 0 inits.
__global__ __launch_bounds__(256) void k_qnorm(const float* __restrict__ q,
                                               float* __restrict__ qn,
                                               unsigned short* __restrict__ qnb,
                                               unsigned short* __restrict__ qnbF,
                                               float* __restrict__ P,
                                               int* __restrict__ cnt,
                                               float* __restrict__ Zt,
                                               float* __restrict__ Ss,
                                               float* __restrict__ ns_,
                                               float* __restrict__ out) {
  const int tid = threadIdx.x, w = tid >> 6, l = tid & 63;
  const int g = l >> 4, qs = l & 15;
  if (blockIdx.x == 0) {
    for (int i = tid; i < C_N * D_N; i += 256) P[i] = 0.f;
    if (tid < C_N) cnt[tid] = 0;
    for (int i = tid; i < B_N; i += 256) { Zt[i] = 0.f; Ss[i] = 0.f; ns_[i] = 0.f; }
    if (tid == 0) out[0] = 0.f;
  }
  const int r = blockIdx.x * 16 + w * 4 + g;
  const float* src = q + (size_t)r * D_N;
  float4 v[4];
#pragma unroll
  for (int c = 0; c < 4; ++c) v[c] = *(const float4*)(src + qs * 4 + c * 64);
  float ss = 0.f;
#pragma unroll
  for (int c = 0; c < 4; ++c)
    ss += v[c].x * v[c].x + v[c].y * v[c].y + v[c].z * v[c].z + v[c].w * v[c].w;
  ss += __shfl_xor(ss, 1, 64);
  ss += __shfl_xor(ss, 2, 64);
  ss += __shfl_xor(ss, 4, 64);
  ss += __shfl_xor(ss, 8, 64);
  const float rv = 1.0f / fmaxf(sqrtf(ss), 1e-8f);
  float* dstf = qn + (size_t)r * D_N;
  unsigned short* dstb = qnb + (size_t)r * D_N;
#pragma unroll
  for (int c = 0; c < 4; ++c) {
    float4 o4;
    o4.x = v[c].x * rv; o4.y = v[c].y * rv; o4.z = v[c].z * rv; o4.w = v[c].w * rv;
    *(float4*)(dstf + qs * 4 + c * 64) = o4;
    ushort4 o;
    o.x = f2bf(o4.x); o.y = f2bf(o4.y); o.z = f2bf(o4.z); o.w = f2bf(o4.w);
    *(ushort4*)(dstb + qs * 4 + c * 64) = o;
    const int kc = (qs >> 1) + c * 8;          // 16B chunk index (0..31)
    *(ushort4*)(qnbF + (((size_t)kc * 512 + r) << 3) + (qs & 1) * 4) = o;
  }
}

// K2 mega-kernel (512 threads = 8 waves):
//   blocks [0,16): src branch (verified).
//   blocks [16,1040): fused pm-norm + Z_mem GEMM, 64 m-rows x ALL 512 q in
//     ONE pass (wave owns 64 q-rows, mi=4: each B-fragment feeds 4 MFMA).
//     A batched per K-quarter into af[8] + sched_barrier pin. B in 544B-pitch
//     LDS (conflict-free). Z -> Zpart; class sums (4-batched) -> part2.
__global__ __launch_bounds__(512, 2) void k_mega(const float* __restrict__ pm,
                                                 const unsigned short* __restrict__ qnb,
                                                 const unsigned short* __restrict__ qnbF,
                                                 const int* __restrict__ labels,
                                                 const int* __restrict__ pl,
                                                 float* __restrict__ Zt,
                                                 float* __restrict__ Ss,
                                                 float* __restrict__ ns_,
                                                 float* __restrict__ Zpart,
                                                 float* __restrict__ part2) {
  __shared__ __align__(16) unsigned char smem[37120];
  const int bid = blockIdx.x;
  const int tid = threadIdx.x, w = tid >> 6, lane = tid & 63;
  const int rsel = lane & 15, hi = lane >> 4;

  if (bid >= 16) {
    // ---------------- fused norm + Z_mem branch ----------------
    const int mt = bid - 16;                               // 0..1023
    unsigned short* Bs = (unsigned short*)smem;            // 64 rows x 544B
    float* zall = (float*)(smem + 34816);                  // [512]
    int* plL = (int*)(smem + 36864);                       // [64]
    const float* Pm = pm + (size_t)mt * 64 * D_N;
    if (tid < 64) plL[tid] = pl[mt * 64 + tid];
    // stage: normalize 64 pm rows -> bf16 LDS tile. quarter-wave rows, 2 passes.
    {
      const int g = lane >> 4, qs = lane & 15;
#pragma unroll 1
      for (int pass = 0; pass < 2; ++pass) {
        const int r = pass * 32 + w * 4 + g;               // local row 0..63
        const float* src = Pm + (size_t)r * D_N;
        float4 v[4];
#pragma unroll
        for (int c = 0; c < 4; ++c) v[c] = *(const float4*)(src + qs * 4 + c * 64);
        float ss = 0.f;
#pragma unroll
        for (int c = 0; c < 4; ++c)
          ss += v[c].x * v[c].x + v[c].y * v[c].y + v[c].z * v[c].z + v[c].w * v[c].w;
        ss += __shfl_xor(ss, 1, 64);
        ss += __shfl_xor(ss, 2, 64);
        ss += __shfl_xor(ss, 4, 64);
        ss += __shfl_xor(ss, 8, 64);
        const float rv = 1.0f / fmaxf(sqrtf(ss), 1e-8f);
#pragma unroll
        for (int c = 0; c < 4; ++c) {
          ushort4 o;
          o.x = f2bf(v[c].x * rv); o.y = f2bf(v[c].y * rv);
          o.z = f2bf(v[c].z * rv); o.w = f2bf(v[c].w * rv);
          *(ushort4*)((char*)Bs + r * 544 + qs * 8 + c * 128) = o;  // elem qs*4+c*64
        }
      }
    }
    __syncthreads();   // the ONLY barrier before the flush

    // GEMM: wave owns q-rows [w*64, w*64+64); 8 waves cover all 512 q.
    f32x4 acc[4][4];
#pragma unroll
    for (int mi = 0; mi < 4; ++mi)
#pragma unroll
      for (int ni = 0; ni < 4; ++ni)
        acc[mi][ni] = (f32x4){0.f, 0.f, 0.f, 0.f};
#pragma unroll 1
    for (int kh = 0; kh < 4; ++kh) {
      bf16x8 af[8];                                        // K-quarter A batch
#pragma unroll
      for (int itl = 0; itl < 2; ++itl)
#pragma unroll
        for (int mi = 0; mi < 4; ++mi)
          af[itl * 4 + mi] = *(const bf16x8*)(qnbF +
              (((size_t)(kh * 8 + itl * 4 + hi) * 512 + w * 64 + mi * 16 + rsel) << 3));
      __builtin_amdgcn_sched_barrier(0);   // pin the batch above the MFMAs
#pragma unroll
      for (int itl = 0; itl < 2; ++itl) {
        const int kc = kh * 8 + itl * 4 + hi;
#pragma unroll
        for (int ni = 0; ni < 4; ++ni) {
          const bf16x8 b = *(const bf16x8*)((const char*)Bs + (ni * 16 + rsel) * 544 + kc * 16);
          acc[0][ni] = __builtin_amdgcn_mfma_f32_16x16x32_bf16(af[itl * 4 + 0], b, acc[0][ni], 0, 0, 0);
          acc[1][ni] = __builtin_amdgcn_mfma_f32_16x16x32_bf16(af[itl * 4 + 1], b, acc[1][ni], 0, 0, 0);
          acc[2][ni] = __builtin_amdgcn_mfma_f32_16x16x32_bf16(af[itl * 4 + 2], b, acc[2][ni], 0, 0, 0);
          acc[3][ni] = __builtin_amdgcn_mfma_f32_16x16x32_bf16(af[itl * 4 + 3], b, acc[3][ni], 0, 0, 0);
        }
      }
    }
    // epilogue: sum exp over this block's 64 m-cols; owner-unique zall stores
#pragma unroll
    for (int mi = 0; mi < 4; ++mi) {
      float sv[4] = {0.f, 0.f, 0.f, 0.f};
#pragma unroll
      for (int ni = 0; ni < 4; ++ni)
#pragma unroll
        for (int rg = 0; rg < 4; ++rg)
          sv[rg] += __builtin_amdgcn_exp2f(acc[mi][ni][rg] * K2C);
#pragma unroll
      for (int rg = 0; rg < 4; ++rg) {
        float v = sv[rg];
        v += __shfl_xor(v, 1, 64);
        v += __shfl_xor(v, 2, 64);
        v += __shfl_xor(v, 4, 64);
        v += __shfl_xor(v, 8, 64);
        if (rsel == 0)
          zall[w * 64 + mi * 16 + hi * 4 + rg] = v;
      }
    }
    __syncthreads();
    Zpart[(size_t)mt * 512 + tid] = zall[tid];             // coalesced, no atomics
    // class partial sums off the LDS tile: thread = (half, dim), 4-batched.
    {
      const int dim = tid & 255, half = tid >> 8;
      float s0 = 0.f, s1 = 0.f, s2 = 0.f, s3 = 0.f, s4 = 0.f;
      float s5 = 0.f, s6 = 0.f, s7 = 0.f, s8 = 0.f, s9 = 0.f;
#pragma unroll 1
      for (int j0 = 0; j0 < 32; j0 += 4) {
        float v[4];
        int cl[4];
#pragma unroll
        for (int u = 0; u < 4; ++u) {
          const int r = half * 32 + j0 + u;
          v[u] = bf2f(*(const unsigned short*)((const char*)Bs + r * 544 + dim * 2));
          cl[u] = plL[r];
        }
#pragma unroll
        for (int u = 0; u < 4; ++u) {
          s0 += (cl[u] == 0) ? v[u] : 0.f;
          s1 += (cl[u] == 1) ? v[u] : 0.f;
          s2 += (cl[u] == 2) ? v[u] : 0.f;
          s3 += (cl[u] == 3) ? v[u] : 0.f;
          s4 += (cl[u] == 4) ? v[u] : 0.f;
          s5 += (cl[u] == 5) ? v[u] : 0.f;
          s6 += (cl[u] == 6) ? v[u] : 0.f;
          s7 += (cl[u] == 7) ? v[u] : 0.f;
          s8 += (cl[u] == 8) ? v[u] : 0.f;
          s9 += (cl[u] == 9) ? v[u] : 0.f;
        }
      }
      float* dst = part2 + ((size_t)mt * 2 + half) * (C_N * D_N) + dim;
      dst[0] = s0; dst[256] = s1; dst[512] = s2; dst[768] = s3; dst[1024] = s4;
      dst[1280] = s5; dst[1536] = s6; dst[1792] = s7; dst[2048] = s8; dst[2304] = s9;
    }
  } else {
    // ---------------- src branch (verified, 8-wave) ----------------
    unsigned short* As = (unsigned short*)smem;            // 128x64
    unsigned short* Bs2 = (unsigned short*)(smem + 16384); // 128x64
    int* labR = (int*)(smem + 32768);
    int* labJ = (int*)(smem + 33280);
    float* zr = (float*)(smem + 33792);
    float* sr = (float*)(smem + 34304);
    float* nr = (float*)(smem + 34816);
    const int bt2 = bid >> 2, jt = bid & 3;
    const unsigned short* Ab = qnb + (size_t)(bt2 * 128) * D_N;
    const unsigned short* Bb = qnb + (size_t)(jt * 128) * D_N;
    if (tid < 128) {
      labR[tid] = labels[bt2 * 128 + tid];
      labJ[tid] = labels[jt * 128 + tid];
      zr[tid] = 0.f; sr[tid] = 0.f; nr[tid] = 0.f;
    }
    f32x4 acc[4][2];
#pragma unroll
    for (int mi = 0; mi < 4; ++mi)
#pragma unroll
      for (int ni = 0; ni < 2; ++ni)
        acc[mi][ni] = (f32x4){0.f, 0.f, 0.f, 0.f};
    const int wr = w >> 2, wc = w & 3;                     // 2 x 4 wave grid
#pragma unroll 1
    for (int ks = 0; ks < 4; ++ks) {
      const int kk = ks * 64;
#pragma unroll
      for (int i = 0; i < 2; ++i) {
        const int cbase = i * 512 + w * 64;
        const int c = cbase + lane;
        const int r = c >> 3;
        const int ss2 = (c & 7) ^ (r & 7);
        __builtin_amdgcn_global_load_lds(
            (const __attribute__((address_space(1))) void*)(Ab + (size_t)r * D_N + kk + ss2 * 8),
            (__attribute__((address_space(3))) void*)(As + cbase * 8), 16, 0, 0);
        __builtin_amdgcn_global_load_lds(
            (const __attribute__((address_space(1))) void*)(Bb + (size_t)r * D_N + kk + ss2 * 8),
            (__attribute__((address_space(3))) void*)(Bs2 + cbase * 8), 16, 0, 0);
      }
      __syncthreads();
#pragma unroll 1
      for (int ksl = 0; ksl < 2; ++ksl) {
        const int sb = ksl * 4 + hi;
        bf16x8 af[4], bfr[2];
#pragma unroll
        for (int mi = 0; mi < 4; ++mi) {
          const int r = wr * 64 + mi * 16 + rsel;
          af[mi] = *(const bf16x8*)((const char*)As + r * 128 + ((sb ^ (r & 7)) * 16));
        }
#pragma unroll
        for (int ni = 0; ni < 2; ++ni) {
          const int r = wc * 32 + ni * 16 + rsel;
          bfr[ni] = *(const bf16x8*)((const char*)Bs2 + r * 128 + ((sb ^ (r & 7)) * 16));
        }
#pragma unroll
        for (int mi = 0; mi < 4; ++mi)
#pragma unroll
          for (int ni = 0; ni < 2; ++ni)
            acc[mi][ni] = __builtin_amdgcn_mfma_f32_16x16x32_bf16(af[mi], bfr[ni], acc[mi][ni], 0, 0, 0);
      }
      __syncthreads();
    }
#pragma unroll
    for (int mi = 0; mi < 4; ++mi) {
      float zs[4] = {0.f, 0.f, 0.f, 0.f};
      float sv[4] = {0.f, 0.f, 0.f, 0.f};
      float nv[4] = {0.f, 0.f, 0.f, 0.f};
#pragma unroll
      for (int ni = 0; ni < 2; ++ni) {
        const int j_loc = wc * 32 + ni * 16 + rsel;
        const int jg = jt * 128 + j_loc;
        const int lj = labJ[j_loc];
#pragma unroll
        for (int rg_ = 0; rg_ < 4; ++rg_) {
          const int r_loc = wr * 64 + mi * 16 + hi * 4 + rg_;
          const int rg = bt2 * 128 + r_loc;
          const float lg = acc[mi][ni][rg_] * TEMP_INV - TEMP_INV;
          if (rg != jg) {
            zs[rg_] += __builtin_amdgcn_exp2f(lg * LOG2E_F);
            if (labR[r_loc] == lj) { sv[rg_] += lg; nv[rg_] += 1.f; }
          }
        }
      }
#pragma unroll
      for (int rg_ = 0; rg_ < 4; ++rg_) {
        float z = zs[rg_], s = sv[rg_], n = nv[rg_];
        z += __shfl_xor(z, 1, 64); z += __shfl_xor(z, 2, 64);
        z += __shfl_xor(z, 4, 64); z += __shfl_xor(z, 8, 64);
        s += __shfl_xor(s, 1, 64); s += __shfl_xor(s, 2, 64);
        s += __shfl_xor(s, 4, 64); s += __shfl_xor(s, 8, 64);
        n += __shfl_xor(n, 1, 64); n += __shfl_xor(n, 2, 64);
        n += __shfl_xor(n, 4, 64); n += __shfl_xor(n, 8, 64);
        if (rsel == 0) {
          const int r_loc = wr * 64 + mi * 16 + hi * 4 + rg_;
          atomicAdd(&zr[r_loc], z);
          atomicAdd(&sr[r_loc], s);
          atomicAdd(&nr[r_loc], n);
        }
      }
    }
    __syncthreads();
    if (tid < 128) {
      atomicAdd(&Zt[bt2 * 128 + tid], zr[tid]);
      atomicAdd(&Ss[bt2 * 128 + tid], sr[tid]);
      atomicAdd(&ns_[bt2 * 128 + tid], nr[tid]);
    }
  }
}

// K3: fused reductions. Blocks [0,40): class partials (2048 rows) -> P, counts.
// Blocks [40,48): Zpart columns (1024 rows) -> Zt (+=).
__global__ __launch_bounds__(256) void k_reduce2(const float* __restrict__ part2,
                                                 const int* __restrict__ pl,
                                                 const float* __restrict__ Zpart,
                                                 float* __restrict__ P,
                                                 int* __restrict__ cnt,
                                                 float* __restrict__ Zt) {
  const int tid = threadIdx.x, w = tid >> 6, lane = tid & 63;
  if (blockIdx.x < 40) {
    __shared__ int xs[4];
    const int c = blockIdx.x >> 2, q = blockIdx.x & 3;
    float s = 0.f;
#pragma unroll 8
    for (int i = 0; i < 512; ++i)
      s += part2[(size_t)(q * 512 + i) * (C_N * D_N) + c * 256 + tid];
    atomicAdd(&P[c * 256 + tid], s);
    int x = 0;
    const int* plq = pl + q * 16384;
#pragma unroll 8
    for (int jj = 0; jj < 64; ++jj)
      x += (plq[jj * 256 + tid] == c) ? 1 : 0;
    x += __shfl_xor(x, 32, 64);
    x += __shfl_xor(x, 16, 64);
    x += __shfl_xor(x, 8, 64);
    x += __shfl_xor(x, 4, 64);
    x += __shfl_xor(x, 2, 64);
    x += __shfl_xor(x, 1, 64);
    if (lane == 0) xs[w] = x;
    __syncthreads();
    if (tid == 0) atomicAdd(&cnt[c], xs[0] + xs[1] + xs[2] + xs[3]);
  } else {
    __shared__ float zl[4][64];
    const int zb = blockIdx.x - 40;
    const int b = zb * 64 + (tid & 63);
    const int s = tid >> 6;
    float acc = 0.f;
#pragma unroll 8
    for (int k = 0; k < 256; ++k)
      acc += Zpart[(size_t)(s * 256 + k) * 512 + b];
    zl[s][tid & 63] = acc;
    __syncthreads();
    if (tid < 64)
      Zt[zb * 64 + tid] += zl[0][tid] + zl[1][tid] + zl[2][tid] + zl[3][tid];
  }
}

// K4: loss. 128 blocks, 1 row per wave.
__global__ __launch_bounds__(256) void k_final(const float* __restrict__ qn,
                                               const int* __restrict__ labels,
                                               const float* __restrict__ P,
                                               const int* __restrict__ cnt,
                                               const float* __restrict__ Zt,
                                               const float* __restrict__ Ss,
                                               const float* __restrict__ ns_,
                                               float* __restrict__ out) {
  __shared__ float partl[4];
  const int tid = threadIdx.x, w = tid >> 6, lane = tid & 63;
  const int b = blockIdx.x * 4 + w;
  const int cls = labels[b];
  const float4 v = *(const float4*)(qn + (size_t)b * D_N + lane * 4);
  const float4 p = *(const float4*)(P + (size_t)cls * D_N + lane * 4);
  float d = v.x * p.x + v.y * p.y + v.z * p.z + v.w * p.w;
  d += __shfl_xor(d, 32, 64);
  d += __shfl_xor(d, 16, 64);
  d += __shfl_xor(d, 8, 64);
  d += __shfl_xor(d, 4, 64);
  d += __shfl_xor(d, 2, 64);
  d += __shfl_xor(d, 1, 64);
  if (lane == 0) {
    const float smem_ = d * TEMP_INV;
    const float ntot = ns_[b] + (float)cnt[cls];
    partl[w] = (Ss[b] + smem_) / ntot - logf(Zt[b]);
  }
  __syncthreads();
  if (tid == 0)
    atomicAdd(out, -(partl[0] + partl[1] + partl[2] + partl[3]) * (1.0f / (float)B_N));
}

extern "C" void kernel_launch(void* const* d_in, const int* in_sizes, int n_in,
                              void* d_out, int out_size, void* d_ws, size_t ws_size,
                              hipStream_t stream) {
  const float* q = (const float*)d_in[0];
  const int* labels = (const int*)d_in[1];
  const float* pm = (const float*)d_in[2];
  const int* pl = (const int*)d_in[3];
  float* out = (float*)d_out;

  char* wsb = (char*)d_ws;
  float* qn = (float*)wsb;                                 // 524,288 B
  unsigned short* qnb = (unsigned short*)(wsb + 524288);   // 262,144 B
  unsigned short* qnbF = (unsigned short*)(wsb + 786432);  // 262,144 B
  float* P = (float*)(wsb + 1048576);                      // 10,240 B
  int* cnt = (int*)(wsb + 1058816);                        // 64 B
  float* Zt = (float*)(wsb + 1058880);                     // 2,048 B
  float* Ss = (float*)(wsb + 1060928);                     // 2,048 B
  float* ns_ = (float*)(wsb + 1062976);                    // 2,048 B
  float* part2 = (float*)(wsb + 1065024);                  // 2048*2560*4 = 20,971,520 B
  float* Zpart = (float*)(wsb + 22036544);                 // 1024*512*4 = 2,097,152 B

  k_qnorm<<<32, 256, 0, stream>>>(q, qn, qnb, qnbF, P, cnt, Zt, Ss, ns_, out);
  k_mega<<<1040, 512, 0, stream>>>(pm, qnb, qnbF, labels, pl, Zt, Ss, ns_, Zpart, part2);
  k_reduce2<<<48, 256, 0, stream>>>(part2, pl, Zpart, P, cnt, Zt);
  k_final<<<128, 256, 0, stream>>>(qn, labels, P, cnt, Zt, Ss, ns_, out);
}

// Round 15
// 86.075 us; speedup vs baseline: 1.1372x; 1.1372x over previous
//
#include <hip/hip_runtime.h>
#include <stdint.h>
#include <math.h>

#define B_N 512
#define M_N 65536
#define D_N 256
#define C_N 10
#define TEMP_INV 14.285714285714286f   // 1/0.07
#define LOG2E_F 1.4426950408889634f
#define K2C (LOG2E_F * TEMP_INV)       // exp(x/T) = exp2(x*K2C)

typedef __attribute__((ext_vector_type(8))) __bf16 bf16x8;
typedef __attribute__((ext_vector_type(4))) float f32x4;

__device__ __forceinline__ unsigned short f2bf(float f) {
  unsigned int u = __float_as_uint(f);
  return (unsigned short)((u + 0x7FFFu + ((u >> 16) & 1u)) >> 16);  // RNE
}
__device__ __forceinline__ float bf2f(unsigned short s) {
  return __uint_as_float(((unsigned int)s) << 16);
}

// K1: q normalize (32 blocks x 256 thr): q -> f32 qn + bf16 qnb (row-major)
// + qnbF (k-chunk-major [kc][r][8] for GEMM A-fragments). Block 0 inits.
__global__ __launch_bounds__(256) void k_qnorm(const float* __restrict__ q,
                                               float* __restrict__ qn,
                                               unsigned short* __restrict__ qnb,
                                               unsigned short* __restrict__ qnbF,
                                               float* __restrict__ P,
                                               int* __restrict__ cnt,
                                               float* __restrict__ Zt,
                                               float* __restrict__ Ss,
                                               float* __restrict__ ns_,
                                               float* __restrict__ out) {
  const int tid = threadIdx.x, w = tid >> 6, l = tid & 63;
  const int g = l >> 4, qs = l & 15;
  if (blockIdx.x == 0) {
    for (int i = tid; i < C_N * D_N; i += 256) P[i] = 0.f;
    if (tid < C_N) cnt[tid] = 0;
    for (int i = tid; i < B_N; i += 256) { Zt[i] = 0.f; Ss[i] = 0.f; ns_[i] = 0.f; }
    if (tid == 0) out[0] = 0.f;
  }
  const int r = blockIdx.x * 16 + w * 4 + g;
  const float* src = q + (size_t)r * D_N;
  float4 v[4];
#pragma unroll
  for (int c = 0; c < 4; ++c) v[c] = *(const float4*)(src + qs * 4 + c * 64);
  float ss = 0.f;
#pragma unroll
  for (int c = 0; c < 4; ++c)
    ss += v[c].x * v[c].x + v[c].y * v[c].y + v[c].z * v[c].z + v[c].w * v[c].w;
  ss += __shfl_xor(ss, 1, 64);
  ss += __shfl_xor(ss, 2, 64);
  ss += __shfl_xor(ss, 4, 64);
  ss += __shfl_xor(ss, 8, 64);
  const float rv = 1.0f / fmaxf(sqrtf(ss), 1e-8f);
  float* dstf = qn + (size_t)r * D_N;
  unsigned short* dstb = qnb + (size_t)r * D_N;
#pragma unroll
  for (int c = 0; c < 4; ++c) {
    float4 o4;
    o4.x = v[c].x * rv; o4.y = v[c].y * rv; o4.z = v[c].z * rv; o4.w = v[c].w * rv;
    *(float4*)(dstf + qs * 4 + c * 64) = o4;
    ushort4 o;
    o.x = f2bf(o4.x); o.y = f2bf(o4.y); o.z = f2bf(o4.z); o.w = f2bf(o4.w);
    *(ushort4*)(dstb + qs * 4 + c * 64) = o;
    const int kc = (qs >> 1) + c * 8;          // 16B chunk index (0..31)
    *(ushort4*)(qnbF + (((size_t)kc * 512 + r) << 3) + (qs & 1) * 4) = o;
  }
}

// K2 mega-kernel (512 threads = 8 waves):
//   blocks [0,16): src branch, 8-wave decomposition (verified).
//   blocks [16,528): fused pm-normalize + Z_mem GEMM, 128 m-rows x 512 q.
//     pm norm -> bf16 LDS (544B pitch). Per wave + q-pass: ALL 16 A-fragments
//     batch-loaded into NAMED registers, FORCIBLY MATERIALIZED via an empty
//     inline-asm with "+v" operands (loads cannot sink past their use).
//     One latency exposure per 64 register-only MFMAs.
__global__ __launch_bounds__(512, 2) void k_mega(const float* __restrict__ pm,
                                                 const unsigned short* __restrict__ qnb,
                                                 const unsigned short* __restrict__ qnbF,
                                                 const int* __restrict__ labels,
                                                 const int* __restrict__ pl,
                                                 float* __restrict__ Zt,
                                                 float* __restrict__ Ss,
                                                 float* __restrict__ ns_,
                                                 float* __restrict__ Zpart,
                                                 float* __restrict__ part2) {
  __shared__ __align__(16) unsigned char smem[72192];
  const int bid = blockIdx.x;
  const int tid = threadIdx.x, w = tid >> 6, lane = tid & 63;
  const int rsel = lane & 15, hi = lane >> 4;

  if (bid >= 16) {
    // ---------------- fused norm + Z_mem branch ----------------
    const int mt = bid - 16;                               // 0..511
    unsigned short* Bs = (unsigned short*)smem;            // 128 rows x 544B
    float* zall = (float*)(smem + 69632);                  // [512]
    int* plL = (int*)(smem + 71680);                       // [128]
    const float* Pm = pm + (size_t)mt * 128 * D_N;
    if (tid < 128) plL[tid] = pl[mt * 128 + tid];
    // stage: normalize 128 pm rows -> bf16 LDS tile. quarter-wave rows, 4 passes.
    {
      const int g = lane >> 4, qs = lane & 15;
#pragma unroll 1
      for (int pass = 0; pass < 4; ++pass) {
        const int r = pass * 32 + w * 4 + g;               // local row 0..127
        const float* src = Pm + (size_t)r * D_N;
        float4 v[4];
#pragma unroll
        for (int c = 0; c < 4; ++c) v[c] = *(const float4*)(src + qs * 4 + c * 64);
        float ss = 0.f;
#pragma unroll
        for (int c = 0; c < 4; ++c)
          ss += v[c].x * v[c].x + v[c].y * v[c].y + v[c].z * v[c].z + v[c].w * v[c].w;
        ss += __shfl_xor(ss, 1, 64);
        ss += __shfl_xor(ss, 2, 64);
        ss += __shfl_xor(ss, 4, 64);
        ss += __shfl_xor(ss, 8, 64);
        const float rv = 1.0f / fmaxf(sqrtf(ss), 1e-8f);
#pragma unroll
        for (int c = 0; c < 4; ++c) {
          ushort4 o;
          o.x = f2bf(v[c].x * rv); o.y = f2bf(v[c].y * rv);
          o.z = f2bf(v[c].z * rv); o.w = f2bf(v[c].w * rv);
          *(ushort4*)((char*)Bs + r * 544 + qs * 8 + c * 128) = o;  // elem qs*4+c*64
        }
      }
    }
    __syncthreads();

#pragma unroll 1
    for (int pass = 0; pass < 2; ++pass) {
      const int qbase = pass * 256 + w * 32;
      // batch-load the wave's ENTIRE A-slice: 16 NAMED registers (64 VGPR).
      bf16x8 af00, af01, af02, af03, af04, af05, af06, af07;
      bf16x8 af10, af11, af12, af13, af14, af15, af16, af17;
#define LA(it_, mi_) *(const bf16x8*)(qnbF + \
        (((size_t)((it_) * 4 + hi) * 512 + qbase + (mi_) * 16 + rsel) << 3))
      af00 = LA(0, 0); af01 = LA(1, 0); af02 = LA(2, 0); af03 = LA(3, 0);
      af04 = LA(4, 0); af05 = LA(5, 0); af06 = LA(6, 0); af07 = LA(7, 0);
      af10 = LA(0, 1); af11 = LA(1, 1); af12 = LA(2, 1); af13 = LA(3, 1);
      af14 = LA(4, 1); af15 = LA(5, 1); af16 = LA(6, 1); af17 = LA(7, 1);
#undef LA
      // PIN: the loads' results are live-in here -> they cannot sink below.
      asm volatile("" : "+v"(af00), "+v"(af01), "+v"(af02), "+v"(af03),
                        "+v"(af04), "+v"(af05), "+v"(af06), "+v"(af07),
                        "+v"(af10), "+v"(af11), "+v"(af12), "+v"(af13),
                        "+v"(af14), "+v"(af15), "+v"(af16), "+v"(af17));
#pragma unroll 1
      for (int mh = 0; mh < 2; ++mh) {
        f32x4 acc[2][4];
#pragma unroll
        for (int ni = 0; ni < 4; ++ni) {
          acc[0][ni] = (f32x4){0.f, 0.f, 0.f, 0.f};
          acc[1][ni] = (f32x4){0.f, 0.f, 0.f, 0.f};
        }
#define GIT(it_, A0, A1)                                                       \
        {                                                                      \
          const int kc = (it_) * 4 + hi;                                       \
          _Pragma("unroll")                                                    \
          for (int ni = 0; ni < 4; ++ni) {                                     \
            const int rB = mh * 64 + ni * 16 + rsel;                           \
            const bf16x8 bfr = *(const bf16x8*)((const char*)Bs + rB * 544 + kc * 16); \
            acc[0][ni] = __builtin_amdgcn_mfma_f32_16x16x32_bf16(A0, bfr, acc[0][ni], 0, 0, 0); \
            acc[1][ni] = __builtin_amdgcn_mfma_f32_16x16x32_bf16(A1, bfr, acc[1][ni], 0, 0, 0); \
          }                                                                    \
        }
        GIT(0, af00, af10)
        GIT(1, af01, af11)
        GIT(2, af02, af12)
        GIT(3, af03, af13)
        GIT(4, af04, af14)
        GIT(5, af05, af15)
        GIT(6, af06, af16)
        GIT(7, af07, af17)
#undef GIT
        // epilogue: sum exp over this m-half's 64 cols
#pragma unroll
        for (int mi = 0; mi < 2; ++mi) {
          float sv[4] = {0.f, 0.f, 0.f, 0.f};
#pragma unroll
          for (int ni = 0; ni < 4; ++ni)
#pragma unroll
            for (int rg = 0; rg < 4; ++rg)
              sv[rg] += __builtin_amdgcn_exp2f(acc[mi][ni][rg] * K2C);
#pragma unroll
          for (int rg = 0; rg < 4; ++rg) {
            float v = sv[rg];
            v += __shfl_xor(v, 1, 64);
            v += __shfl_xor(v, 2, 64);
            v += __shfl_xor(v, 4, 64);
            v += __shfl_xor(v, 8, 64);
            if (rsel == 0) {
              const int qi = qbase + mi * 16 + hi * 4 + rg;  // owner-unique
              if (mh == 0) zall[qi] = v; else zall[qi] += v;
            }
          }
        }
      }
    }
    __syncthreads();
    Zpart[(size_t)mt * 512 + tid] = zall[tid];             // coalesced, no atomics
    // class partial sums off the LDS tile: thread = (half, dim), branchless.
    {
      const int dim = tid & 255, half = tid >> 8;
      float s0 = 0.f, s1 = 0.f, s2 = 0.f, s3 = 0.f, s4 = 0.f;
      float s5 = 0.f, s6 = 0.f, s7 = 0.f, s8 = 0.f, s9 = 0.f;
#pragma unroll 4
      for (int j = 0; j < 64; ++j) {
        const int r = half * 64 + j;
        const float v = bf2f(*(const unsigned short*)((const char*)Bs + r * 544 + dim * 2));
        const int cls = plL[r];
        s0 += (cls == 0) ? v : 0.f;
        s1 += (cls == 1) ? v : 0.f;
        s2 += (cls == 2) ? v : 0.f;
        s3 += (cls == 3) ? v : 0.f;
        s4 += (cls == 4) ? v : 0.f;
        s5 += (cls == 5) ? v : 0.f;
        s6 += (cls == 6) ? v : 0.f;
        s7 += (cls == 7) ? v : 0.f;
        s8 += (cls == 8) ? v : 0.f;
        s9 += (cls == 9) ? v : 0.f;
      }
      float* dst = part2 + ((size_t)mt * 2 + half) * (C_N * D_N) + dim;
      dst[0] = s0; dst[256] = s1; dst[512] = s2; dst[768] = s3; dst[1024] = s4;
      dst[1280] = s5; dst[1536] = s6; dst[1792] = s7; dst[2048] = s8; dst[2304] = s9;
    }
  } else {
    // ---------------- src branch (verified math, 8-wave decomposition) ----------------
    unsigned short* As = (unsigned short*)smem;            // 128x64
    unsigned short* Bs2 = (unsigned short*)(smem + 16384); // 128x64
    int* labR = (int*)(smem + 32768);
    int* labJ = (int*)(smem + 33280);
    float* zr = (float*)(smem + 33792);
    float* sr = (float*)(smem + 34304);
    float* nr = (float*)(smem + 34816);
    const int bt2 = bid >> 2, jt = bid & 3;
    const unsigned short* Ab = qnb + (size_t)(bt2 * 128) * D_N;
    const unsigned short* Bb = qnb + (size_t)(jt * 128) * D_N;
    if (tid < 128) {
      labR[tid] = labels[bt2 * 128 + tid];
      labJ[tid] = labels[jt * 128 + tid];
      zr[tid] = 0.f; sr[tid] = 0.f; nr[tid] = 0.f;
    }
    f32x4 acc[4][2];                                       // 64 rows x 32 cols per wave
#pragma unroll
    for (int mi = 0; mi < 4; ++mi)
#pragma unroll
      for (int ni = 0; ni < 2; ++ni)
        acc[mi][ni] = (f32x4){0.f, 0.f, 0.f, 0.f};
    const int wr = w >> 2, wc = w & 3;                     // 2 x 4 wave grid
#pragma unroll 1
    for (int ks = 0; ks < 4; ++ks) {
      const int kk = ks * 64;
#pragma unroll
      for (int i = 0; i < 2; ++i) {
        const int cbase = i * 512 + w * 64;
        const int c = cbase + lane;
        const int r = c >> 3;
        const int ss2 = (c & 7) ^ (r & 7);
        __builtin_amdgcn_global_load_lds(
            (const __attribute__((address_space(1))) void*)(Ab + (size_t)r * D_N + kk + ss2 * 8),
            (__attribute__((address_space(3))) void*)(As + cbase * 8), 16, 0, 0);
        __builtin_amdgcn_global_load_lds(
            (const __attribute__((address_space(1))) void*)(Bb + (size_t)r * D_N + kk + ss2 * 8),
            (__attribute__((address_space(3))) void*)(Bs2 + cbase * 8), 16, 0, 0);
      }
      __syncthreads();
#pragma unroll 1
      for (int ksl = 0; ksl < 2; ++ksl) {
        const int sb = ksl * 4 + hi;
        bf16x8 af[4], bfr[2];
#pragma unroll
        for (int mi = 0; mi < 4; ++mi) {
          const int r = wr * 64 + mi * 16 + rsel;
          af[mi] = *(const bf16x8*)((const char*)As + r * 128 + ((sb ^ (r & 7)) * 16));
        }
#pragma unroll
        for (int ni = 0; ni < 2; ++ni) {
          const int r = wc * 32 + ni * 16 + rsel;
          bfr[ni] = *(const bf16x8*)((const char*)Bs2 + r * 128 + ((sb ^ (r & 7)) * 16));
        }
#pragma unroll
        for (int mi = 0; mi < 4; ++mi)
#pragma unroll
          for (int ni = 0; ni < 2; ++ni)
            acc[mi][ni] = __builtin_amdgcn_mfma_f32_16x16x32_bf16(af[mi], bfr[ni], acc[mi][ni], 0, 0, 0);
      }
      __syncthreads();
    }
#pragma unroll
    for (int mi = 0; mi < 4; ++mi) {
      float zs[4] = {0.f, 0.f, 0.f, 0.f};
      float sv[4] = {0.f, 0.f, 0.f, 0.f};
      float nv[4] = {0.f, 0.f, 0.f, 0.f};
#pragma unroll
      for (int ni = 0; ni < 2; ++ni) {
        const int j_loc = wc * 32 + ni * 16 + rsel;
        const int jg = jt * 128 + j_loc;
        const int lj = labJ[j_loc];
#pragma unroll
        for (int rg_ = 0; rg_ < 4; ++rg_) {
          const int r_loc = wr * 64 + mi * 16 + hi * 4 + rg_;
          const int rg = bt2 * 128 + r_loc;
          const float lg = acc[mi][ni][rg_] * TEMP_INV - TEMP_INV;
          if (rg != jg) {
            zs[rg_] += __builtin_amdgcn_exp2f(lg * LOG2E_F);
            if (labR[r_loc] == lj) { sv[rg_] += lg; nv[rg_] += 1.f; }
          }
        }
      }
#pragma unroll
      for (int rg_ = 0; rg_ < 4; ++rg_) {
        float z = zs[rg_], s = sv[rg_], n = nv[rg_];
        z += __shfl_xor(z, 1, 64); z += __shfl_xor(z, 2, 64);
        z += __shfl_xor(z, 4, 64); z += __shfl_xor(z, 8, 64);
        s += __shfl_xor(s, 1, 64); s += __shfl_xor(s, 2, 64);
        s += __shfl_xor(s, 4, 64); s += __shfl_xor(s, 8, 64);
        n += __shfl_xor(n, 1, 64); n += __shfl_xor(n, 2, 64);
        n += __shfl_xor(n, 4, 64); n += __shfl_xor(n, 8, 64);
        if (rsel == 0) {
          const int r_loc = wr * 64 + mi * 16 + hi * 4 + rg_;
          atomicAdd(&zr[r_loc], z);
          atomicAdd(&sr[r_loc], s);
          atomicAdd(&nr[r_loc], n);
        }
      }
    }
    __syncthreads();
    if (tid < 128) {
      atomicAdd(&Zt[bt2 * 128 + tid], zr[tid]);
      atomicAdd(&Ss[bt2 * 128 + tid], sr[tid]);
      atomicAdd(&ns_[bt2 * 128 + tid], nr[tid]);
    }
  }
}

// K3: fused reductions. Blocks [0,40): class partials (1024 rows) -> P, counts.
// Blocks [40,48): Zpart columns (512 rows) -> Zt (+=).
__global__ __launch_bounds__(256) void k_reduce2(const float* __restrict__ part2,
                                                 const int* __restrict__ pl,
                                                 const float* __restrict__ Zpart,
                                                 float* __restrict__ P,
                                                 int* __restrict__ cnt,
                                                 float* __restrict__ Zt) {
  const int tid = threadIdx.x, w = tid >> 6, lane = tid & 63;
  if (blockIdx.x < 40) {
    __shared__ int xs[4];
    const int c = blockIdx.x >> 2, q = blockIdx.x & 3;
    float s = 0.f;
#pragma unroll 8
    for (int i = 0; i < 256; ++i)
      s += part2[(size_t)(q * 256 + i) * (C_N * D_N) + c * 256 + tid];
    atomicAdd(&P[c * 256 + tid], s);
    int x = 0;
    const int* plq = pl + q * 16384;
#pragma unroll 8
    for (int jj = 0; jj < 64; ++jj)
      x += (plq[jj * 256 + tid] == c) ? 1 : 0;
    x += __shfl_xor(x, 32, 64);
    x += __shfl_xor(x, 16, 64);
    x += __shfl_xor(x, 8, 64);
    x += __shfl_xor(x, 4, 64);
    x += __shfl_xor(x, 2, 64);
    x += __shfl_xor(x, 1, 64);
    if (lane == 0) xs[w] = x;
    __syncthreads();
    if (tid == 0) atomicAdd(&cnt[c], xs[0] + xs[1] + xs[2] + xs[3]);
  } else {
    __shared__ float zl[4][64];
    const int zb = blockIdx.x - 40;
    const int b = zb * 64 + (tid & 63);
    const int s = tid >> 6;
    float acc = 0.f;
#pragma unroll 8
    for (int k = 0; k < 128; ++k)
      acc += Zpart[(size_t)(s * 128 + k) * 512 + b];
    zl[s][tid & 63] = acc;
    __syncthreads();
    if (tid < 64)
      Zt[zb * 64 + tid] += zl[0][tid] + zl[1][tid] + zl[2][tid] + zl[3][tid];
  }
}

// K4: loss. 128 blocks, 1 row per wave.
__global__ __launch_bounds__(256) void k_final(const float* __restrict__ qn,
                                               const int* __restrict__ labels,
                                               const float* __restrict__ P,
                                               const int* __restrict__ cnt,
                                               const float* __restrict__ Zt,
                                               const float* __restrict__ Ss,
                                               const float* __restrict__ ns_,
                                               float* __restrict__ out) {
  __shared__ float partl[4];
  const int tid = threadIdx.x, w = tid >> 6, lane = tid & 63;
  const int b = blockIdx.x * 4 + w;
  const int cls = labels[b];
  const float4 v = *(const float4*)(qn + (size_t)b * D_N + lane * 4);
  const float4 p = *(const float4*)(P + (size_t)cls * D_N + lane * 4);
  float d = v.x * p.x + v.y * p.y + v.z * p.z + v.w * p.w;
  d += __shfl_xor(d, 32, 64);
  d += __shfl_xor(d, 16, 64);
  d += __shfl_xor(d, 8, 64);
  d += __shfl_xor(d, 4, 64);
  d += __shfl_xor(d, 2, 64);
  d += __shfl_xor(d, 1, 64);
  if (lane == 0) {
    const float smem_ = d * TEMP_INV;
    const float ntot = ns_[b] + (float)cnt[cls];
    partl[w] = (Ss[b] + smem_) / ntot - logf(Zt[b]);
  }
  __syncthreads();
  if (tid == 0)
    atomicAdd(out, -(partl[0] + partl[1] + partl[2] + partl[3]) * (1.0f / (float)B_N));
}

extern "C" void kernel_launch(void* const* d_in, const int* in_sizes, int n_in,
                              void* d_out, int out_size, void* d_ws, size_t ws_size,
                              hipStream_t stream) {
  const float* q = (const float*)d_in[0];
  const int* labels = (const int*)d_in[1];
  const float* pm = (const float*)d_in[2];
  const int* pl = (const int*)d_in[3];
  float* out = (float*)d_out;

  char* wsb = (char*)d_ws;
  float* qn = (float*)wsb;                                 // 524,288 B
  unsigned short* qnb = (unsigned short*)(wsb + 524288);   // 262,144 B
  unsigned short* qnbF = (unsigned short*)(wsb + 786432);  // 262,144 B
  float* P = (float*)(wsb + 1048576);                      // 10,240 B
  int* cnt = (int*)(wsb + 1058816);                        // 64 B
  float* Zt = (float*)(wsb + 1058880);                     // 2,048 B
  float* Ss = (float*)(wsb + 1060928);                     // 2,048 B
  float* ns_ = (float*)(wsb + 1062976);                    // 2,048 B
  float* part2 = (float*)(wsb + 1065024);                  // 1024*2560*4 = 10,485,760 B
  float* Zpart = (float*)(wsb + 11550784);                 // 512*512*4 = 1,048,576 B

  k_qnorm<<<32, 256, 0, stream>>>(q, qn, qnb, qnbF, P, cnt, Zt, Ss, ns_, out);
  k_mega<<<528, 512, 0, stream>>>(pm, qnb, qnbF, labels, pl, Zt, Ss, ns_, Zpart, part2);
  k_reduce2<<<48, 256, 0, stream>>>(part2, pl, Zpart, P, cnt, Zt);
  k_final<<<128, 256, 0, stream>>>(qn, labels, P, cnt, Zt, Ss, ns_, out);
}

// Round 16
// 75.517 us; speedup vs baseline: 1.2962x; 1.1398x over previous
//
#include <hip/hip_runtime.h>
#include <stdint.h>
#include <math.h>

#define B_N 512
#define M_N 65536
#define D_N 256
#define C_N 10
#define TEMP_INV 14.285714285714286f   // 1/0.07
#define LOG2E_F 1.4426950408889634f
#define K2C (LOG2E_F * TEMP_INV)       // exp(x/T) = exp2(x*K2C)

typedef __attribute__((ext_vector_type(8))) __bf16 bf16x8;
typedef __attribute__((ext_vector_type(4))) float f32x4;

__device__ __forceinline__ unsigned short f2bf(float f) {
  unsigned int u = __float_as_uint(f);
  return (unsigned short)((u + 0x7FFFu + ((u >> 16) & 1u)) >> 16);  // RNE
}
__device__ __forceinline__ float bf2f(unsigned short s) {
  return __uint_as_float(((unsigned int)s) << 16);
}

// K1: q normalize (32 blocks x 256 thr): q -> f32 qn + bf16 qnb (row-major)
// + qnbF (k-chunk-major [kc][r][8] for GEMM A-fragments). Block 0 inits.
__global__ __launch_bounds__(256) void k_qnorm(const float* __restrict__ q,
                                               float* __restrict__ qn,
                                               unsigned short* __restrict__ qnb,
                                               unsigned short* __restrict__ qnbF,
                                               float* __restrict__ P,
                                               int* __restrict__ cnt,
                                               float* __restrict__ Zt,
                                               float* __restrict__ Ss,
                                               float* __restrict__ ns_,
                                               float* __restrict__ out) {
  const int tid = threadIdx.x, w = tid >> 6, l = tid & 63;
  const int g = l >> 4, qs = l & 15;
  if (blockIdx.x == 0) {
    for (int i = tid; i < C_N * D_N; i += 256) P[i] = 0.f;
    if (tid < C_N) cnt[tid] = 0;
    for (int i = tid; i < B_N; i += 256) { Zt[i] = 0.f; Ss[i] = 0.f; ns_[i] = 0.f; }
    if (tid == 0) out[0] = 0.f;
  }
  const int r = blockIdx.x * 16 + w * 4 + g;
  const float* src = q + (size_t)r * D_N;
  float4 v[4];
#pragma unroll
  for (int c = 0; c < 4; ++c) v[c] = *(const float4*)(src + qs * 4 + c * 64);
  float ss = 0.f;
#pragma unroll
  for (int c = 0; c < 4; ++c)
    ss += v[c].x * v[c].x + v[c].y * v[c].y + v[c].z * v[c].z + v[c].w * v[c].w;
  ss += __shfl_xor(ss, 1, 64);
  ss += __shfl_xor(ss, 2, 64);
  ss += __shfl_xor(ss, 4, 64);
  ss += __shfl_xor(ss, 8, 64);
  const float rv = 1.0f / fmaxf(sqrtf(ss), 1e-8f);
  float* dstf = qn + (size_t)r * D_N;
  unsigned short* dstb = qnb + (size_t)r * D_N;
#pragma unroll
  for (int c = 0; c < 4; ++c) {
    float4 o4;
    o4.x = v[c].x * rv; o4.y = v[c].y * rv; o4.z = v[c].z * rv; o4.w = v[c].w * rv;
    *(float4*)(dstf + qs * 4 + c * 64) = o4;
    ushort4 o;
    o.x = f2bf(o4.x); o.y = f2bf(o4.y); o.z = f2bf(o4.z); o.w = f2bf(o4.w);
    *(ushort4*)(dstb + qs * 4 + c * 64) = o;
    const int kc = (qs >> 1) + c * 8;          // 16B chunk index (0..31)
    *(ushort4*)(qnbF + (((size_t)kc * 512 + r) << 3) + (qs & 1) * 4) = o;
  }
}

// K2 mega-kernel (512 threads = 8 waves):
//   blocks [0,16): src branch, 8-wave decomposition (verified).
//   blocks [16,528): fused pm-normalize + Z_mem GEMM, 128 m-rows x 512 q.
//     pm norm -> bf16 LDS (544B pitch). Per wave + q-pass: ALL 16 A-fragments
//     batch-loaded into registers, reused across two m-halves.
//     Z -> Zpart; class sums -> part2.
__global__ __launch_bounds__(512, 4) void k_mega(const float* __restrict__ pm,
                                                 const unsigned short* __restrict__ qnb,
                                                 const unsigned short* __restrict__ qnbF,
                                                 const int* __restrict__ labels,
                                                 const int* __restrict__ pl,
                                                 float* __restrict__ Zt,
                                                 float* __restrict__ Ss,
                                                 float* __restrict__ ns_,
                                                 float* __restrict__ Zpart,
                                                 float* __restrict__ part2) {
  __shared__ __align__(16) unsigned char smem[72192];
  const int bid = blockIdx.x;
  const int tid = threadIdx.x, w = tid >> 6, lane = tid & 63;
  const int rsel = lane & 15, hi = lane >> 4;

  if (bid >= 16) {
    // ---------------- fused norm + Z_mem branch ----------------
    const int mt = bid - 16;                               // 0..511
    unsigned short* Bs = (unsigned short*)smem;            // 128 rows x 544B
    float* zall = (float*)(smem + 69632);                  // [512]
    int* plL = (int*)(smem + 71680);                       // [128]
    const float* Pm = pm + (size_t)mt * 128 * D_N;
    if (tid < 128) plL[tid] = pl[mt * 128 + tid];
    // stage: normalize 128 pm rows -> bf16 LDS tile. quarter-wave rows, 4 passes.
    {
      const int g = lane >> 4, qs = lane & 15;
#pragma unroll
      for (int pass = 0; pass < 4; ++pass) {
        const int r = pass * 32 + w * 4 + g;               // local row 0..127
        const float* src = Pm + (size_t)r * D_N;
        float4 v[4];
#pragma unroll
        for (int c = 0; c < 4; ++c) v[c] = *(const float4*)(src + qs * 4 + c * 64);
        float ss = 0.f;
#pragma unroll
        for (int c = 0; c < 4; ++c)
          ss += v[c].x * v[c].x + v[c].y * v[c].y + v[c].z * v[c].z + v[c].w * v[c].w;
        ss += __shfl_xor(ss, 1, 64);
        ss += __shfl_xor(ss, 2, 64);
        ss += __shfl_xor(ss, 4, 64);
        ss += __shfl_xor(ss, 8, 64);
        const float rv = 1.0f / fmaxf(sqrtf(ss), 1e-8f);
#pragma unroll
        for (int c = 0; c < 4; ++c) {
          ushort4 o;
          o.x = f2bf(v[c].x * rv); o.y = f2bf(v[c].y * rv);
          o.z = f2bf(v[c].z * rv); o.w = f2bf(v[c].w * rv);
          *(ushort4*)((char*)Bs + r * 544 + qs * 8 + c * 128) = o;  // elem qs*4+c*64
        }
      }
    }
    __syncthreads();   // the ONLY barrier before the flush

#pragma unroll
    for (int pass = 0; pass < 2; ++pass) {
      const int qbase = pass * 256 + w * 32;
      // batch-load the wave's ENTIRE A-slice for this q-pass: 16 independent
      // loads -> 64 VGPRs, one latency exposure, reused across both m-halves.
      bf16x8 af[2][8];
#pragma unroll
      for (int it = 0; it < 8; ++it)
#pragma unroll
        for (int mi = 0; mi < 2; ++mi)
          af[mi][it] = *(const bf16x8*)(qnbF +
              (((size_t)(it * 4 + hi) * 512 + qbase + mi * 16 + rsel) << 3));
#pragma unroll
      for (int mh = 0; mh < 2; ++mh) {
        f32x4 acc[2][4];
#pragma unroll
        for (int mi = 0; mi < 2; ++mi)
#pragma unroll
          for (int ni = 0; ni < 4; ++ni)
            acc[mi][ni] = (f32x4){0.f, 0.f, 0.f, 0.f};
#pragma unroll
        for (int it = 0; it < 8; ++it) {
          const int kc = it * 4 + hi;
#pragma unroll
          for (int ni = 0; ni < 4; ++ni) {
            const int rB = mh * 64 + ni * 16 + rsel;
            const bf16x8 bfr = *(const bf16x8*)((const char*)Bs + rB * 544 + kc * 16);
            acc[0][ni] = __builtin_amdgcn_mfma_f32_16x16x32_bf16(af[0][it], bfr, acc[0][ni], 0, 0, 0);
            acc[1][ni] = __builtin_amdgcn_mfma_f32_16x16x32_bf16(af[1][it], bfr, acc[1][ni], 0, 0, 0);
          }
        }
        // epilogue: sum exp over this m-half's 64 cols
#pragma unroll
        for (int mi = 0; mi < 2; ++mi) {
          float sv[4] = {0.f, 0.f, 0.f, 0.f};
#pragma unroll
          for (int ni = 0; ni < 4; ++ni)
#pragma unroll
            for (int rg = 0; rg < 4; ++rg)
              sv[rg] += __builtin_amdgcn_exp2f(acc[mi][ni][rg] * K2C);
#pragma unroll
          for (int rg = 0; rg < 4; ++rg) {
            float v = sv[rg];
            v += __shfl_xor(v, 1, 64);
            v += __shfl_xor(v, 2, 64);
            v += __shfl_xor(v, 4, 64);
            v += __shfl_xor(v, 8, 64);
            if (rsel == 0) {
              const int qi = qbase + mi * 16 + hi * 4 + rg;  // owner-unique
              if (mh == 0) zall[qi] = v; else zall[qi] += v;
            }
          }
        }
      }
    }
    __syncthreads();
    Zpart[(size_t)mt * 512 + tid] = zall[tid];             // coalesced, no atomics
    // class partial sums off the LDS tile: thread = (half, dim), branchless.
    {
      const int dim = tid & 255, half = tid >> 8;
      float s0 = 0.f, s1 = 0.f, s2 = 0.f, s3 = 0.f, s4 = 0.f;
      float s5 = 0.f, s6 = 0.f, s7 = 0.f, s8 = 0.f, s9 = 0.f;
#pragma unroll 4
      for (int j = 0; j < 64; ++j) {
        const int r = half * 64 + j;
        const float v = bf2f(*(const unsigned short*)((const char*)Bs + r * 544 + dim * 2));
        const int cls = plL[r];
        s0 += (cls == 0) ? v : 0.f;
        s1 += (cls == 1) ? v : 0.f;
        s2 += (cls == 2) ? v : 0.f;
        s3 += (cls == 3) ? v : 0.f;
        s4 += (cls == 4) ? v : 0.f;
        s5 += (cls == 5) ? v : 0.f;
        s6 += (cls == 6) ? v : 0.f;
        s7 += (cls == 7) ? v : 0.f;
        s8 += (cls == 8) ? v : 0.f;
        s9 += (cls == 9) ? v : 0.f;
      }
      float* dst = part2 + ((size_t)mt * 2 + half) * (C_N * D_N) + dim;
      dst[0] = s0; dst[256] = s1; dst[512] = s2; dst[768] = s3; dst[1024] = s4;
      dst[1280] = s5; dst[1536] = s6; dst[1792] = s7; dst[2048] = s8; dst[2304] = s9;
    }
  } else {
    // ---------------- src branch (verified math, 8-wave decomposition) ----------------
    unsigned short* As = (unsigned short*)smem;            // 128x64
    unsigned short* Bs2 = (unsigned short*)(smem + 16384); // 128x64
    int* labR = (int*)(smem + 32768);
    int* labJ = (int*)(smem + 33280);
    float* zr = (float*)(smem + 33792);
    float* sr = (float*)(smem + 34304);
    float* nr = (float*)(smem + 34816);
    const int bt2 = bid >> 2, jt = bid & 3;
    const unsigned short* Ab = qnb + (size_t)(bt2 * 128) * D_N;
    const unsigned short* Bb = qnb + (size_t)(jt * 128) * D_N;
    if (tid < 128) {
      labR[tid] = labels[bt2 * 128 + tid];
      labJ[tid] = labels[jt * 128 + tid];
      zr[tid] = 0.f; sr[tid] = 0.f; nr[tid] = 0.f;
    }
    f32x4 acc[4][2];                                       // 64 rows x 32 cols per wave
#pragma unroll
    for (int mi = 0; mi < 4; ++mi)
#pragma unroll
      for (int ni = 0; ni < 2; ++ni)
        acc[mi][ni] = (f32x4){0.f, 0.f, 0.f, 0.f};
    const int wr = w >> 2, wc = w & 3;                     // 2 x 4 wave grid
    for (int ks = 0; ks < 4; ++ks) {
      const int kk = ks * 64;
#pragma unroll
      for (int i = 0; i < 2; ++i) {
        const int cbase = i * 512 + w * 64;
        const int c = cbase + lane;
        const int r = c >> 3;
        const int ss2 = (c & 7) ^ (r & 7);
        __builtin_amdgcn_global_load_lds(
            (const __attribute__((address_space(1))) void*)(Ab + (size_t)r * D_N + kk + ss2 * 8),
            (__attribute__((address_space(3))) void*)(As + cbase * 8), 16, 0, 0);
        __builtin_amdgcn_global_load_lds(
            (const __attribute__((address_space(1))) void*)(Bb + (size_t)r * D_N + kk + ss2 * 8),
            (__attribute__((address_space(3))) void*)(Bs2 + cbase * 8), 16, 0, 0);
      }
      __syncthreads();
#pragma unroll
      for (int ksl = 0; ksl < 2; ++ksl) {
        const int sb = ksl * 4 + hi;
        bf16x8 af[4], bfr[2];
#pragma unroll
        for (int mi = 0; mi < 4; ++mi) {
          const int r = wr * 64 + mi * 16 + rsel;
          af[mi] = *(const bf16x8*)((const char*)As + r * 128 + ((sb ^ (r & 7)) * 16));
        }
#pragma unroll
        for (int ni = 0; ni < 2; ++ni) {
          const int r = wc * 32 + ni * 16 + rsel;
          bfr[ni] = *(const bf16x8*)((const char*)Bs2 + r * 128 + ((sb ^ (r & 7)) * 16));
        }
#pragma unroll
        for (int mi = 0; mi < 4; ++mi)
#pragma unroll
          for (int ni = 0; ni < 2; ++ni)
            acc[mi][ni] = __builtin_amdgcn_mfma_f32_16x16x32_bf16(af[mi], bfr[ni], acc[mi][ni], 0, 0, 0);
      }
      __syncthreads();
    }
#pragma unroll
    for (int mi = 0; mi < 4; ++mi) {
      float zs[4] = {0.f, 0.f, 0.f, 0.f};
      float sv[4] = {0.f, 0.f, 0.f, 0.f};
      float nv[4] = {0.f, 0.f, 0.f, 0.f};
#pragma unroll
      for (int ni = 0; ni < 2; ++ni) {
        const int j_loc = wc * 32 + ni * 16 + rsel;
        const int jg = jt * 128 + j_loc;
        const int lj = labJ[j_loc];
#pragma unroll
        for (int rg_ = 0; rg_ < 4; ++rg_) {
          const int r_loc = wr * 64 + mi * 16 + hi * 4 + rg_;
          const int rg = bt2 * 128 + r_loc;
          const float lg = acc[mi][ni][rg_] * TEMP_INV - TEMP_INV;
          if (rg != jg) {
            zs[rg_] += __builtin_amdgcn_exp2f(lg * LOG2E_F);
            if (labR[r_loc] == lj) { sv[rg_] += lg; nv[rg_] += 1.f; }
          }
        }
      }
#pragma unroll
      for (int rg_ = 0; rg_ < 4; ++rg_) {
        float z = zs[rg_], s = sv[rg_], n = nv[rg_];
        z += __shfl_xor(z, 1, 64); z += __shfl_xor(z, 2, 64);
        z += __shfl_xor(z, 4, 64); z += __shfl_xor(z, 8, 64);
        s += __shfl_xor(s, 1, 64); s += __shfl_xor(s, 2, 64);
        s += __shfl_xor(s, 4, 64); s += __shfl_xor(s, 8, 64);
        n += __shfl_xor(n, 1, 64); n += __shfl_xor(n, 2, 64);
        n += __shfl_xor(n, 4, 64); n += __shfl_xor(n, 8, 64);
        if (rsel == 0) {
          const int r_loc = wr * 64 + mi * 16 + hi * 4 + rg_;
          atomicAdd(&zr[r_loc], z);
          atomicAdd(&sr[r_loc], s);
          atomicAdd(&nr[r_loc], n);
        }
      }
    }
    __syncthreads();
    if (tid < 128) {
      atomicAdd(&Zt[bt2 * 128 + tid], zr[tid]);
      atomicAdd(&Ss[bt2 * 128 + tid], sr[tid]);
      atomicAdd(&ns_[bt2 * 128 + tid], nr[tid]);
    }
  }
}

// K3: fused reductions. Blocks [0,40): class partials (1024 rows) -> P, counts.
// Blocks [40,48): Zpart columns (512 rows) -> Zt (+=).
__global__ __launch_bounds__(256) void k_reduce2(const float* __restrict__ part2,
                                                 const int* __restrict__ pl,
                                                 const float* __restrict__ Zpart,
                                                 float* __restrict__ P,
                                                 int* __restrict__ cnt,
                                                 float* __restrict__ Zt) {
  const int tid = threadIdx.x, w = tid >> 6, lane = tid & 63;
  if (blockIdx.x < 40) {
    __shared__ int xs[4];
    const int c = blockIdx.x >> 2, q = blockIdx.x & 3;
    float s = 0.f;
#pragma unroll 8
    for (int i = 0; i < 256; ++i)
      s += part2[(size_t)(q * 256 + i) * (C_N * D_N) + c * 256 + tid];
    atomicAdd(&P[c * 256 + tid], s);
    int x = 0;
    const int* plq = pl + q * 16384;
#pragma unroll 8
    for (int jj = 0; jj < 64; ++jj)
      x += (plq[jj * 256 + tid] == c) ? 1 : 0;
    x += __shfl_xor(x, 32, 64);
    x += __shfl_xor(x, 16, 64);
    x += __shfl_xor(x, 8, 64);
    x += __shfl_xor(x, 4, 64);
    x += __shfl_xor(x, 2, 64);
    x += __shfl_xor(x, 1, 64);
    if (lane == 0) xs[w] = x;
    __syncthreads();
    if (tid == 0) atomicAdd(&cnt[c], xs[0] + xs[1] + xs[2] + xs[3]);
  } else {
    __shared__ float zl[4][64];
    const int zb = blockIdx.x - 40;
    const int b = zb * 64 + (tid & 63);
    const int s = tid >> 6;
    float acc = 0.f;
#pragma unroll 8
    for (int k = 0; k < 128; ++k)
      acc += Zpart[(size_t)(s * 128 + k) * 512 + b];
    zl[s][tid & 63] = acc;
    __syncthreads();
    if (tid < 64)
      Zt[zb * 64 + tid] += zl[0][tid] + zl[1][tid] + zl[2][tid] + zl[3][tid];
  }
}

// K4: loss. 128 blocks, 1 row per wave.
__global__ __launch_bounds__(256) void k_final(const float* __restrict__ qn,
                                               const int* __restrict__ labels,
                                               const float* __restrict__ P,
                                               const int* __restrict__ cnt,
                                               const float* __restrict__ Zt,
                                               const float* __restrict__ Ss,
                                               const float* __restrict__ ns_,
                                               float* __restrict__ out) {
  __shared__ float partl[4];
  const int tid = threadIdx.x, w = tid >> 6, lane = tid & 63;
  const int b = blockIdx.x * 4 + w;
  const int cls = labels[b];
  const float4 v = *(const float4*)(qn + (size_t)b * D_N + lane * 4);
  const float4 p = *(const float4*)(P + (size_t)cls * D_N + lane * 4);
  float d = v.x * p.x + v.y * p.y + v.z * p.z + v.w * p.w;
  d += __shfl_xor(d, 32, 64);
  d += __shfl_xor(d, 16, 64);
  d += __shfl_xor(d, 8, 64);
  d += __shfl_xor(d, 4, 64);
  d += __shfl_xor(d, 2, 64);
  d += __shfl_xor(d, 1, 64);
  if (lane == 0) {
    const float smem_ = d * TEMP_INV;
    const float ntot = ns_[b] + (float)cnt[cls];
    partl[w] = (Ss[b] + smem_) / ntot - logf(Zt[b]);
  }
  __syncthreads();
  if (tid == 0)
    atomicAdd(out, -(partl[0] + partl[1] + partl[2] + partl[3]) * (1.0f / (float)B_N));
}

extern "C" void kernel_launch(void* const* d_in, const int* in_sizes, int n_in,
                              void* d_out, int out_size, void* d_ws, size_t ws_size,
                              hipStream_t stream) {
  const float* q = (const float*)d_in[0];
  const int* labels = (const int*)d_in[1];
  const float* pm = (const float*)d_in[2];
  const int* pl = (const int*)d_in[3];
  float* out = (float*)d_out;

  char* wsb = (char*)d_ws;
  float* qn = (float*)wsb;                                 // 524,288 B
  unsigned short* qnb = (unsigned short*)(wsb + 524288);   // 262,144 B
  unsigned short* qnbF = (unsigned short*)(wsb + 786432);  // 262,144 B
  float* P = (float*)(wsb + 1048576);                      // 10,240 B
  int* cnt = (int*)(wsb + 1058816);                        // 64 B
  float* Zt = (float*)(wsb + 1058880);                     // 2,048 B
  float* Ss = (float*)(wsb + 1060928);                     // 2,048 B
  float* ns_ = (float*)(wsb + 1062976);                    // 2,048 B
  float* part2 = (float*)(wsb + 1065024);                  // 1024*2560*4 = 10,485,760 B
  float* Zpart = (float*)(wsb + 11550784);                 // 512*512*4 = 1,048,576 B

  k_qnorm<<<32, 256, 0, stream>>>(q, qn, qnb, qnbF, P, cnt, Zt, Ss, ns_, out);
  k_mega<<<528, 512, 0, stream>>>(pm, qnb, qnbF, labels, pl, Zt, Ss, ns_, Zpart, part2);
  k_reduce2<<<48, 256, 0, stream>>>(part2, pl, Zpart, P, cnt, Zt);
  k_final<<<128, 256, 0, stream>>>(qn, labels, P, cnt, Zt, Ss, ns_, out);
}